// Round 1
// baseline (386.721 us; speedup 1.0000x reference)
//
#include <hip/hip_runtime.h>

#define A_N 100000
#define B_N 8
#define C_N 80
#define M_N 32

// Workspace layout (floats): [0:8) cls_sum, [8:16) reg_sum, [16:24) npos (as int)

__global__ __launch_bounds__(256) void focal_main(
    const float4* __restrict__ cls4,   // [B, A, 20] as float4 (C=80 floats/anchor)
    const float4* __restrict__ reg4,   // [B, A] float4
    const float4* __restrict__ anc4,   // [A] float4
    const float*  __restrict__ ann,    // [B, 32, 9]
    float* __restrict__ cls_sum, float* __restrict__ reg_sum, int* __restrict__ npos)
{
    __shared__ float annL[M_N][6];          // x0,y0,x1,y1,label,area
    __shared__ unsigned char stateL[256];   // 0=bg, 1=ignore, 2=pos
    __shared__ unsigned char clsIdxL[256];
    __shared__ float redA[4];
    __shared__ int   redI[4];
    __shared__ float redB[4];

    const int b   = blockIdx.y;
    const int a0  = blockIdx.x * 256;
    const int tid = threadIdx.x;

    // --- load annotations for this image into LDS ---
    for (int i = tid; i < M_N * 5; i += 256) {
        int m = i / 5, c = i % 5;
        annL[m][c] = ann[(b * M_N + m) * 9 + c];
    }
    __syncthreads();
    if (tid < M_N) {
        annL[tid][5] = (annL[tid][2] - annL[tid][0]) * (annL[tid][3] - annL[tid][1]);
    }
    __syncthreads();

    // --- Phase A: per-anchor assignment + regression loss ---
    const int a = a0 + tid;
    const bool valid = a < A_N;
    float regacc = 0.0f;
    bool pos = false;
    int st = 1;   // invalid anchors behave as "ignore" (contribute 0); never read in phase B anyway
    int ci = 0;

    if (valid) {
        float4 an = anc4[a];
        float aw = an.z - an.x, ah = an.w - an.y;
        float aArea = aw * ah;
        float best = -1.0f; int bidx = 0;
        #pragma unroll 8
        for (int m = 0; m < M_N; ++m) {
            float iw = fminf(an.z, annL[m][2]) - fmaxf(an.x, annL[m][0]);
            float ih = fminf(an.w, annL[m][3]) - fmaxf(an.y, annL[m][1]);
            iw = fmaxf(iw, 0.0f); ih = fmaxf(ih, 0.0f);
            float inter = iw * ih;
            float ua = fmaxf(aArea + annL[m][5] - inter, 1e-8f);
            float iou = inter / ua;
            if (iou > best) { best = iou; bidx = m; }   // strict > == first-max (JAX argmax)
        }
        pos = best >= 0.5f;
        st  = pos ? 2 : (best < 0.4f ? 0 : 1);
        ci  = (int)annL[bidx][4];

        if (pos) {
            float4 r = reg4[(size_t)b * A_N + a];
            float gx0 = annL[bidx][0], gy0 = annL[bidx][1];
            float gx1 = annL[bidx][2], gy1 = annL[bidx][3];
            float gwr = gx1 - gx0, ghr = gy1 - gy0;
            float gcx = gx0 + 0.5f * gwr, gcy = gy0 + 0.5f * ghr;
            float gw = fmaxf(gwr, 1.0f), gh = fmaxf(ghr, 1.0f);
            float acx = an.x + 0.5f * aw, acy = an.y + 0.5f * ah;
            // tgt / [0.1,0.1,0.2,0.2]
            float t0 = (gcx - acx) / aw * 10.0f;
            float t1 = (gcy - acy) / ah * 10.0f;
            float t2 = __logf(gw / aw) * 5.0f;
            float t3 = __logf(gh / ah) * 5.0f;
            float d0 = fabsf(t0 - r.x), d1 = fabsf(t1 - r.y);
            float d2 = fabsf(t2 - r.z), d3 = fabsf(t3 - r.w);
            const float th = 1.0f / 9.0f;
            const float hs = 0.5f / 9.0f;
            regacc  = (d0 <= th) ? 4.5f * d0 * d0 : d0 - hs;
            regacc += (d1 <= th) ? 4.5f * d1 * d1 : d1 - hs;
            regacc += (d2 <= th) ? 4.5f * d2 * d2 : d2 - hs;
            regacc += (d3 <= th) ? 4.5f * d3 * d3 : d3 - hs;
        }
    }
    stateL[tid]  = (unsigned char)st;
    clsIdxL[tid] = (unsigned char)ci;

    // reduce num_pos + reg loss: wave shuffle -> LDS -> thread 0 atomic
    unsigned long long bal = __ballot(pos);
    #pragma unroll
    for (int o = 32; o > 0; o >>= 1) regacc += __shfl_down(regacc, o, 64);
    int lane = tid & 63, wid = tid >> 6;
    if (lane == 0) { redA[wid] = regacc; redI[wid] = __popcll(bal); }
    __syncthreads();   // also publishes stateL/clsIdxL for phase B
    if (tid == 0) {
        float rs = redA[0] + redA[1] + redA[2] + redA[3];
        int   np = redI[0] + redI[1] + redI[2] + redI[3];
        if (rs != 0.0f) atomicAdd(&reg_sum[b], rs);
        if (np)         atomicAdd(&npos[b], np);
    }

    // --- Phase B: stream classifications, coalesced float4 ---
    const float4* cbase = cls4 + ((size_t)b * A_N + a0) * 20;
    const int nA = min(256, A_N - a0);
    const int n4 = nA * 20;
    float clsacc = 0.0f;
    for (int i = tid; i < n4; i += 256) {
        int la  = i / 20;
        int st2 = stateL[la];
        if (st2 == 1) continue;            // ignored anchor: skip the load entirely
        float4 v = cbase[i];
        int ciL = clsIdxL[la];
        int c0  = (i % 20) * 4;
        float pv[4] = {v.x, v.y, v.z, v.w};
        #pragma unroll
        for (int j = 0; j < 4; ++j) {
            float p = fminf(fmaxf(pv[j], 1e-4f), 1.0f - 1e-4f);
            bool one = (st2 == 2) && (c0 + j == ciL);
            float alphaf = one ? 0.25f : 0.75f;
            float w      = one ? 1.0f - p : p;
            float arg    = one ? p : 1.0f - p;   // single log, branchless
            clsacc += alphaf * w * w * (-__logf(arg));
        }
    }
    #pragma unroll
    for (int o = 32; o > 0; o >>= 1) clsacc += __shfl_down(clsacc, o, 64);
    if (lane == 0) redB[wid] = clsacc;
    __syncthreads();
    if (tid == 0) {
        float cs = redB[0] + redB[1] + redB[2] + redB[3];
        atomicAdd(&cls_sum[b], cs);
    }
}

__global__ void focal_finalize(const float* __restrict__ cls_sum,
                               const float* __restrict__ reg_sum,
                               const int* __restrict__ npos,
                               float* __restrict__ out)
{
    if (threadIdx.x == 0) {
        float c = 0.0f, r = 0.0f;
        for (int b = 0; b < B_N; ++b) {
            float np = (float)npos[b];
            c += cls_sum[b] / fmaxf(np, 1.0f);
            r += (npos[b] > 0) ? reg_sum[b] / (4.0f * np) : 0.0f;
        }
        out[0] = c / (float)B_N;
        out[1] = r / (float)B_N;
    }
}

extern "C" void kernel_launch(void* const* d_in, const int* in_sizes, int n_in,
                              void* d_out, int out_size, void* d_ws, size_t ws_size,
                              hipStream_t stream) {
    const float* cls = (const float*)d_in[0];   // [B, A, C]
    const float* reg = (const float*)d_in[1];   // [B, A, 4]
    const float* anc = (const float*)d_in[2];   // [1, A, 4]
    const float* ann = (const float*)d_in[3];   // [B, M, 9]

    float* ws      = (float*)d_ws;
    float* cls_sum = ws;
    float* reg_sum = ws + 8;
    int*   npos    = (int*)(ws + 16);

    hipMemsetAsync(d_ws, 0, 24 * sizeof(float), stream);

    dim3 grid((A_N + 255) / 256, B_N);
    focal_main<<<grid, 256, 0, stream>>>(
        (const float4*)cls, (const float4*)reg, (const float4*)anc, ann,
        cls_sum, reg_sum, npos);

    focal_finalize<<<1, 64, 0, stream>>>(cls_sum, reg_sum, npos, (float*)d_out);
}

// Round 3
// 385.682 us; speedup vs baseline: 1.0027x; 1.0027x over previous
//
#include <hip/hip_runtime.h>

#define A_N 100000
#define B_N 8
#define C_N 80
#define M_N 32

typedef float vfloat4 __attribute__((ext_vector_type(4)));  // clang-native: OK for nontemporal builtin

// Workspace layout (floats): [0:8) cls_sum, [8:16) reg_sum, [16:24) npos (as int)

__global__ __launch_bounds__(256) void focal_main(
    const vfloat4* __restrict__ cls4,  // [B, A, 20] as float4 (C=80 floats/anchor)
    const float4* __restrict__ reg4,   // [B, A] float4
    const float4* __restrict__ anc4,   // [A] float4
    const float*  __restrict__ ann,    // [B, 32, 9]
    float* __restrict__ cls_sum, float* __restrict__ reg_sum, int* __restrict__ npos)
{
    __shared__ float annL[M_N][6];   // x0,y0,x1,y1,label,area
    __shared__ int   metaL[256];     // state (2 bits) | clsIdx<<2
    __shared__ float redA[4];
    __shared__ int   redI[4];
    __shared__ float redB[4];

    const int b   = blockIdx.y;
    const int a0  = blockIdx.x * 256;
    const int tid = threadIdx.x;

    // --- load annotations for this image into LDS ---
    for (int i = tid; i < M_N * 5; i += 256) {
        int m = i / 5, c = i % 5;
        annL[m][c] = ann[(b * M_N + m) * 9 + c];
    }
    __syncthreads();
    if (tid < M_N) {
        annL[tid][5] = (annL[tid][2] - annL[tid][0]) * (annL[tid][3] - annL[tid][1]);
    }
    __syncthreads();

    // --- Phase A: per-anchor assignment + regression loss ---
    const int a = a0 + tid;
    const bool valid = a < A_N;
    float regacc = 0.0f;
    bool pos = false;
    int st = 1;   // invalid anchors behave as "ignore" (contribute 0); never streamed in phase B
    int ci = 0;

    if (valid) {
        float4 an = anc4[a];
        float aw = an.z - an.x, ah = an.w - an.y;
        float aArea = aw * ah;
        float best = -1.0f; int bidx = 0;
        #pragma unroll 8
        for (int m = 0; m < M_N; ++m) {
            float iw = fminf(an.z, annL[m][2]) - fmaxf(an.x, annL[m][0]);
            float ih = fminf(an.w, annL[m][3]) - fmaxf(an.y, annL[m][1]);
            iw = fmaxf(iw, 0.0f); ih = fmaxf(ih, 0.0f);
            float inter = iw * ih;
            float ua = fmaxf(aArea + annL[m][5] - inter, 1e-8f);
            float iou = inter / ua;
            if (iou > best) { best = iou; bidx = m; }   // strict > == first-max (JAX argmax)
        }
        pos = best >= 0.5f;
        st  = pos ? 2 : (best < 0.4f ? 0 : 1);
        ci  = (int)annL[bidx][4];

        if (pos) {
            float4 r = reg4[(size_t)b * A_N + a];
            float gx0 = annL[bidx][0], gy0 = annL[bidx][1];
            float gx1 = annL[bidx][2], gy1 = annL[bidx][3];
            float gwr = gx1 - gx0, ghr = gy1 - gy0;
            float gcx = gx0 + 0.5f * gwr, gcy = gy0 + 0.5f * ghr;
            float gw = fmaxf(gwr, 1.0f), gh = fmaxf(ghr, 1.0f);
            float acx = an.x + 0.5f * aw, acy = an.y + 0.5f * ah;
            float t0 = (gcx - acx) / aw * 10.0f;
            float t1 = (gcy - acy) / ah * 10.0f;
            float t2 = __logf(gw / aw) * 5.0f;
            float t3 = __logf(gh / ah) * 5.0f;
            float d0 = fabsf(t0 - r.x), d1 = fabsf(t1 - r.y);
            float d2 = fabsf(t2 - r.z), d3 = fabsf(t3 - r.w);
            const float th = 1.0f / 9.0f;
            const float hs = 0.5f / 9.0f;
            regacc  = (d0 <= th) ? 4.5f * d0 * d0 : d0 - hs;
            regacc += (d1 <= th) ? 4.5f * d1 * d1 : d1 - hs;
            regacc += (d2 <= th) ? 4.5f * d2 * d2 : d2 - hs;
            regacc += (d3 <= th) ? 4.5f * d3 * d3 : d3 - hs;
        }
    }
    metaL[tid] = st | (ci << 2);

    // reduce num_pos + reg loss: wave shuffle -> LDS -> thread 0 atomic
    unsigned long long bal = __ballot(pos);
    #pragma unroll
    for (int o = 32; o > 0; o >>= 1) regacc += __shfl_down(regacc, o, 64);
    int lane = tid & 63, wid = tid >> 6;
    if (lane == 0) { redA[wid] = regacc; redI[wid] = __popcll(bal); }
    __syncthreads();   // also publishes metaL for phase B
    if (tid == 0) {
        float rs = redA[0] + redA[1] + redA[2] + redA[3];
        int   np = redI[0] + redI[1] + redI[2] + redI[3];
        if (rs != 0.0f) atomicAdd(&reg_sum[b], rs);
        if (np)         atomicAdd(&npos[b], np);
    }

    // --- Phase B: stream classifications, branchless, coalesced nontemporal float4 ---
    const vfloat4* cbase = cls4 + ((size_t)b * A_N + a0) * 20;
    const int nA = min(256, A_N - a0);
    float clsacc = 0.0f;

    if (nA == 256) {
        // full tile: 5120 float4s, 20 trips/thread, no bounds checks, no data-dependent branches
        #pragma unroll 4
        for (int k = 0; k < 20; ++k) {
            int i   = tid + (k << 8);
            vfloat4 v = __builtin_nontemporal_load(cbase + i);
            int la  = i / 20;
            int c0  = (i - la * 20) * 4;
            int m   = metaL[la];
            int st2 = m & 3;
            int ciL = m >> 2;
            float notIgn = (st2 != 1) ? 1.0f : 0.0f;
            bool  isPos  = (st2 == 2);
            float pv[4] = {v.x, v.y, v.z, v.w};
            float term = 0.0f;
            #pragma unroll
            for (int j = 0; j < 4; ++j) {
                float p = fminf(fmaxf(pv[j], 1e-4f), 1.0f - 1e-4f);
                bool one = isPos && (c0 + j == ciL);
                float alphaf = one ? 0.25f : 0.75f;
                float w      = one ? 1.0f - p : p;
                float arg    = one ? p : 1.0f - p;   // single log, branchless
                term += alphaf * w * w * (-__logf(arg));
            }
            clsacc += notIgn * term;
        }
    } else {
        const int n4 = nA * 20;
        for (int i = tid; i < n4; i += 256) {
            vfloat4 v = __builtin_nontemporal_load(cbase + i);
            int la  = i / 20;
            int c0  = (i - la * 20) * 4;
            int m   = metaL[la];
            int st2 = m & 3;
            int ciL = m >> 2;
            float notIgn = (st2 != 1) ? 1.0f : 0.0f;
            bool  isPos  = (st2 == 2);
            float pv[4] = {v.x, v.y, v.z, v.w};
            float term = 0.0f;
            #pragma unroll
            for (int j = 0; j < 4; ++j) {
                float p = fminf(fmaxf(pv[j], 1e-4f), 1.0f - 1e-4f);
                bool one = isPos && (c0 + j == ciL);
                float alphaf = one ? 0.25f : 0.75f;
                float w      = one ? 1.0f - p : p;
                float arg    = one ? p : 1.0f - p;
                term += alphaf * w * w * (-__logf(arg));
            }
            clsacc += notIgn * term;
        }
    }

    #pragma unroll
    for (int o = 32; o > 0; o >>= 1) clsacc += __shfl_down(clsacc, o, 64);
    if (lane == 0) redB[wid] = clsacc;
    __syncthreads();
    if (tid == 0) {
        float cs = redB[0] + redB[1] + redB[2] + redB[3];
        atomicAdd(&cls_sum[b], cs);
    }
}

__global__ void focal_finalize(const float* __restrict__ cls_sum,
                               const float* __restrict__ reg_sum,
                               const int* __restrict__ npos,
                               float* __restrict__ out)
{
    if (threadIdx.x == 0) {
        float c = 0.0f, r = 0.0f;
        for (int b = 0; b < B_N; ++b) {
            float np = (float)npos[b];
            c += cls_sum[b] / fmaxf(np, 1.0f);
            r += (npos[b] > 0) ? reg_sum[b] / (4.0f * np) : 0.0f;
        }
        out[0] = c / (float)B_N;
        out[1] = r / (float)B_N;
    }
}

extern "C" void kernel_launch(void* const* d_in, const int* in_sizes, int n_in,
                              void* d_out, int out_size, void* d_ws, size_t ws_size,
                              hipStream_t stream) {
    const float* cls = (const float*)d_in[0];   // [B, A, C]
    const float* reg = (const float*)d_in[1];   // [B, A, 4]
    const float* anc = (const float*)d_in[2];   // [1, A, 4]
    const float* ann = (const float*)d_in[3];   // [B, M, 9]

    float* ws      = (float*)d_ws;
    float* cls_sum = ws;
    float* reg_sum = ws + 8;
    int*   npos    = (int*)(ws + 16);

    (void)hipMemsetAsync(d_ws, 0, 24 * sizeof(float), stream);

    dim3 grid((A_N + 255) / 256, B_N);
    focal_main<<<grid, 256, 0, stream>>>(
        (const vfloat4*)cls, (const float4*)reg, (const float4*)anc, ann,
        cls_sum, reg_sum, npos);

    focal_finalize<<<1, 64, 0, stream>>>(cls_sum, reg_sum, npos, (float*)d_out);
}